// Round 10
// baseline (30.420 us; speedup 1.0000x reference)
//
#include <hip/hip_runtime.h>
#include <math.h>
#include <stdint.h>

// Problem dims (fixed): B=8, C=128, M=16, H=W=128
#define NB 8
#define NC 128
#define NM 16
#define HW (128*128)        // 16384 positions
#define NOUTM 15
#define CHW 2               // channels per wave
#define WAVES 8             // waves per block (512 threads)
#define CHB (CHW*WAVES)     // 16 channels per block
#define NCT (NC / CHB)      // 8 channel tiles
#define PCHUNK 8            // position chunks -> grid 8*8*8 = 512 blocks
#define POSC (HW / PCHUNK)  // 2048 positions per chunk
#define G4 (POSC / 4)       // 512 float4-groups per chunk
#define NITER (G4 / 64)     // 8 iterations per wave
#define NINF_PK 0xFC00FC00u // packed f16 {-inf,-inf}

__device__ __forceinline__ uint32_t pkmax(uint32_t a, uint32_t b) {
    uint32_t d;
    asm("v_pk_max_f16 %0, %1, %2" : "=v"(d) : "v"(a), "v"(b));
    return d;
}
__device__ __forceinline__ uint32_t bfi(uint32_t s, uint32_t a, uint32_t b) {
    uint32_t d;
    asm("v_bfi_b32 %0, %1, %2, %3" : "=v"(d) : "v"(s), "v"(a), "v"(b));
    return d;
}
__device__ __forceinline__ uint32_t cvt_dup(float f) {
    auto h = __builtin_amdgcn_cvt_pkrtz(f, f);   // monotone RTZ f32->f16 x2
    return __builtin_bit_cast(uint32_t, h);
}
__device__ __forceinline__ float h2f(uint32_t h16) {
    unsigned short u = (unsigned short)h16;
    __fp16 h = __builtin_bit_cast(__fp16, u);
    return (float)h;
}
// Exact f32 atomic max via CAS (values only grow from -inf).
__device__ __forceinline__ void atomicMaxF(float* addr, float val) {
    int* ia = (int*)addr;
    int cur = __float_as_int(-INFINITY);
    while (__int_as_float(cur) < val) {
        int prev = atomicCAS(ia, cur, __float_as_int(val));
        if (prev == cur) break;
        cur = prev;
    }
}

// ---------------------------------------------------------------------------
// Kernel 1: pack 15 mask planes into a bitmask per (b,pos).
// int4 loads; planes split 4-way across thread groups (4/4/4/3), partial
// bitmasks OR-combined through LDS.  Also inits out[] to -inf (stream-
// ordered before kernel 2; re-runs every replay -> deterministic).
// ---------------------------------------------------------------------------
__global__ __launch_bounds__(256) void pack_masks_k(
        const int* __restrict__ masks, uint32_t* __restrict__ packed,
        float* __restrict__ out) {
    int t    = threadIdx.x;
    int gid  = blockIdx.x * 64 + (t & 63);   // int4-group id, 0..32767
    int pset = t >> 6;                        // 0..3 -> planes 4/4/4/3
    int b    = gid >> 12;                     // 4096 groups per batch
    int p4   = gid & 4095;
    const int* mb = masks + (size_t)b * NM * HW + (size_t)p4 * 4;

    uint32_t b0 = 0, b1 = 0, b2 = 0, b3 = 0;
    int mlo = pset * 4 + 1;
    int mhi = (pset == 3) ? 15 : (mlo + 3);   // inclusive
    #pragma unroll
    for (int m = 1; m < NM; ++m) {
        if (m >= mlo && m <= mhi) {
            int4 mm = *(const int4*)(mb + (size_t)m * HW);
            int sh = m - 1;
            b0 |= ((uint32_t)mm.x) << sh;     // mask values are 0/1
            b1 |= ((uint32_t)mm.y) << sh;
            b2 |= ((uint32_t)mm.z) << sh;
            b3 |= ((uint32_t)mm.w) << sh;
        }
    }

    __shared__ uint4 lds[4][64];
    lds[pset][t & 63] = make_uint4(b0, b1, b2, b3);
    __syncthreads();
    if (t < 64) {
        uint4 a = lds[0][t], c = lds[1][t], d = lds[2][t], e = lds[3][t];
        uint4 r = make_uint4(a.x | c.x | d.x | e.x,
                             a.y | c.y | d.y | e.y,
                             a.z | c.z | d.z | e.z,
                             a.w | c.w | d.w | e.w);
        *(uint4*)(packed + (size_t)gid * 4) = r;
    }

    int flat = blockIdx.x * 256 + t;
    if (flat < NB * NC * NOUTM) out[flat] = -INFINITY;
}

// ---------------------------------------------------------------------------
// Kernel 2: wave-per-channel-pair.  Block = 8 waves x 64 lanes; wave w owns
// channels {ctile*16 + 2w, +1}.  Each wave streams 3 contiguous streams
// (2 encoded planes + shared bits), 8 float4-iters.  acc = 16 packed-f16
// words (VGPR ~60, no LDS).  In-register 64-lane butterfly reduce; 30 f32
// CAS atomic-max per wave directly into out.
// ---------------------------------------------------------------------------
#define DO_POS2(BW, FA, FB)                                                   \
    {                                                                         \
        uint32_t ua = cvt_dup(FA), ub = cvt_dup(FB);                          \
        uint32_t bw_ = (BW);                                                  \
        _Pragma("unroll") for (int mp = 0; mp < 8; ++mp) {                    \
            uint32_t lo = (uint32_t)((int32_t)(bw_ << (31 - 2 * mp)) >> 31);  \
            uint32_t hi = (uint32_t)((int32_t)(bw_ << (30 - 2 * mp)) >> 31);  \
            uint32_t s01 = __builtin_amdgcn_perm(hi, lo, 0x05040100u);        \
            acc[mp]     = pkmax(acc[mp],     bfi(s01, ua, NINF_PK));          \
            acc[8 + mp] = pkmax(acc[8 + mp], bfi(s01, ub, NINF_PK));          \
        }                                                                     \
    }

__global__ __launch_bounds__(512, 4) void region_partial_k(
        const float* __restrict__ encoded,
        const uint32_t* __restrict__ packed,
        float* __restrict__ out) {
    int chunk = blockIdx.x;            // 0..PCHUNK-1
    int ctile = blockIdx.y;            // 0..NCT-1
    int b     = blockIdx.z;            // 0..NB-1
    int t     = threadIdx.x;
    int lane  = t & 63;
    int wave  = t >> 6;
    int ch0   = ctile * CHB + wave * CHW;

    const uint4*  bits4 = (const uint4*)(packed + (size_t)b * HW
                                         + (size_t)chunk * POSC);
    const float4* e4    = (const float4*)(encoded
                          + ((size_t)b * NC + ch0) * HW
                          + (size_t)chunk * POSC);

    uint32_t acc[16];
    #pragma unroll
    for (int w = 0; w < 16; ++w) acc[w] = NINF_PK;

    #pragma unroll
    for (int g = 0; g < NITER; ++g) {          // 8 iterations
        int i = g * 64 + lane;
        uint4  bb = bits4[i];
        float4 va = e4[i];                     // channel ch0
        float4 vb = e4[i + (HW / 4)];          // channel ch0+1
        DO_POS2(bb.x, va.x, vb.x)
        DO_POS2(bb.y, va.y, vb.y)
        DO_POS2(bb.z, va.z, vb.z)
        DO_POS2(bb.w, va.w, vb.w)
    }

    // in-register 64-lane butterfly reduce (all lanes end with the result)
    #pragma unroll
    for (int w = 0; w < 16; ++w) {
        uint32_t v = acc[w];
        #pragma unroll
        for (int off = 32; off >= 1; off >>= 1)
            v = pkmax(v, (uint32_t)__shfl_xor((int)v, off, 64));
        acc[w] = v;
    }

    // lane-mapped epilogue: lane = ch2*16 + mp*2 + half  (30 valid of 32)
    if (lane < 32) {
        int ch2 = lane >> 4, mp = (lane >> 1) & 7, half = lane & 1;
        int m = mp * 2 + half;
        if (m < NOUTM) {
            int widx = ch2 * 8 + mp;
            uint32_t wv = 0;
            #pragma unroll
            for (int w = 0; w < 16; ++w) wv = (w == widx) ? acc[w] : wv;
            float f = h2f(half ? (wv >> 16) : (wv & 0xFFFFu));
            int c = ch0 + ch2;
            atomicMaxF(out + ((size_t)b * NC + c) * NOUTM + m, f);
        }
    }
}

extern "C" void kernel_launch(void* const* d_in, const int* in_sizes, int n_in,
                              void* d_out, int out_size, void* d_ws, size_t ws_size,
                              hipStream_t stream) {
    const float* encoded = (const float*)d_in[0];   // [8,128,128,128] f32
    const int*   masks   = (const int*)d_in[1];     // [8,16,128,128] i32
    float*       out     = (float*)d_out;           // [8,128,15,1] f32

    uint32_t* packed = (uint32_t*)d_ws;             // 512 KB

    pack_masks_k<<<512, 256, 0, stream>>>(masks, packed, out);

    dim3 grid2(PCHUNK, NCT, NB);   // 8 x 8 x 8 = 512 blocks x 512 thr
    region_partial_k<<<grid2, 512, 0, stream>>>(encoded, packed, out);
}